// Round 3
// baseline (231.986 us; speedup 1.0000x reference)
//
#include <hip/hip_runtime.h>

#define BB 64
#define CC 128
#define TT 4096
#define NN 6            // KNOT + 2
#define HH 819.0f       // (T-1)/(KNOT+1) = 4095/5, exact in fp32
#define NTHR 512
#define EPT 8           // curve elements per thread (NTHR*EPT == TT)
#define NWAVE (NTHR / 64)

typedef float f4 __attribute__((ext_vector_type(4)));

__device__ __forceinline__ void nt_store4(float* p, f4 v) {
    __builtin_nontemporal_store(v, (f4*)p);
}

// LDS pad: +1 float per 32 breaks power-of-2 stride conflicts.
// Scatter writes at q ~= 8*lane land 2 lanes/bank (free); restage float4
// reads stay contiguous within each 32-float block (base%4==0).
__device__ __forceinline__ int padi(int j) { return j + (j >> 5); }

__global__ __launch_bounds__(NTHR) void timewarp_kernel(
    const float* __restrict__ x,
    const float* __restrict__ yy,
    const float* __restrict__ mask_rand,
    float* __restrict__ out)
{
    const int row = blockIdx.x;          // b*C + c
    const int b   = row / CC;
    const int c   = row % CC;
    const int tid = threadIdx.x;

    const float* xrow = x + (size_t)row * TT;
    float* orow       = out + (size_t)row * TT;

    // mask_rand >= 0.5 -> bit-exact copy (uniform per block)
    if (!(mask_rand[b] < 0.5f)) {
        const f4* xi = (const f4*)xrow;
        nt_store4(orow + 4 * tid,          xi[tid]);
        nt_store4(orow + 4 * (tid + NTHR), xi[tid + NTHR]);
        return;
    }

    __shared__ float sh_res[TT + TT / 32];   // final values, padded scatter target
    __shared__ float sh_xx[NTHR];            // xp boundary exchange (bit-exact)
    __shared__ float sh_fx[NTHR];            // fp boundary exchange
    __shared__ float sh_wsum[NWAVE];         // per-wave scan totals

    // ---- load this thread's 8 consecutive x values ----
    const int t0 = tid * EPT;
    float fpv[EPT];
    {
        const f4 v0 = *(const f4*)(xrow + t0);
        const f4 v1 = *(const f4*)(xrow + t0 + 4);
        fpv[0] = v0.x; fpv[1] = v0.y; fpv[2] = v0.z; fpv[3] = v0.w;
        fpv[4] = v1.x; fpv[5] = v1.y; fpv[6] = v1.z; fpv[7] = v1.w;
    }
    sh_fx[tid] = fpv[0];                     // fenced by B1

    // ---- 6x6 not-a-knot solve, redundantly on every thread ----
    // A is compile-time constant -> elimination multipliers fold to constants;
    // yy addresses are block-uniform -> scalar loads. No barrier needed.
    float Mv[NN];
    float y[NN];
    {
        #pragma unroll
        for (int k = 0; k < NN; ++k)
            y[k] = yy[((size_t)b * NN + k) * CC + c];
        float Aug[NN][NN + 1];
        #pragma unroll
        for (int i = 0; i < NN; ++i)
            #pragma unroll
            for (int j = 0; j < NN + 1; ++j)
                Aug[i][j] = 0.0f;
        Aug[0][0] = 1.0f;  Aug[0][1] = -2.0f;  Aug[0][2] = 1.0f;
        Aug[5][3] = 1.0f;  Aug[5][4] = -2.0f;  Aug[5][5] = 1.0f;
        #pragma unroll
        for (int i = 1; i < NN - 1; ++i) {
            Aug[i][i - 1] = HH / 6.0f;
            Aug[i][i]     = 2.0f * HH / 3.0f;
            Aug[i][i + 1] = HH / 6.0f;
            Aug[i][NN]    = (y[i + 1] - 2.0f * y[i] + y[i - 1]) / HH;
        }
        #pragma unroll
        for (int k = 0; k < NN; ++k) {
            float inv = 1.0f / Aug[k][k];
            #pragma unroll
            for (int i = k + 1; i < NN; ++i) {
                float m = Aug[i][k] * inv;
                #pragma unroll
                for (int j = k; j < NN + 1; ++j)
                    Aug[i][j] -= m * Aug[k][j];
            }
        }
        #pragma unroll
        for (int i = NN - 1; i >= 0; --i) {
            float s = Aug[i][NN];
            #pragma unroll
            for (int j = i + 1; j < NN; ++j)
                s -= Aug[i][j] * Mv[j];
            Mv[i] = s / Aug[i][i];
        }
    }

    // ---- per-thread span Horner coefficients (STATIC register indexing) ----
    // 8 consecutive t's cross at most one knot boundary (span = 819 >> 8).
    // curve(s) = a + s*(b + s*(c + s*d)), s = t - xl
    int idxA = t0 / 819;  if (idxA > 4) idxA = 4;
    int idxB = idxA + 1;  if (idxB > 4) idxB = 4;
    float MiA = Mv[0], Mi1A = Mv[1], yiA = y[0], yi1A = y[1];
    #pragma unroll
    for (int s = 1; s <= 4; ++s)
        if (idxA >= s) { MiA = Mv[s]; Mi1A = Mv[s + 1]; yiA = y[s]; yi1A = y[s + 1]; }
    float MiB = Mv[0], Mi1B = Mv[1], yiB = y[0], yi1B = y[1];
    #pragma unroll
    for (int s = 1; s <= 4; ++s)
        if (idxB >= s) { MiB = Mv[s]; Mi1B = Mv[s + 1]; yiB = y[s]; yi1B = y[s + 1]; }
    const float invh  = 1.0f / HH;
    const float inv6h = 1.0f / (6.0f * HH);
    const float aA = yiA;
    const float bA = (yi1A - yiA) * invh - MiA * (HH / 3.0f) - Mi1A * (HH / 6.0f);
    const float cA = MiA * 0.5f;
    const float dA = (Mi1A - MiA) * inv6h;
    const float aB = yiB;
    const float bB = (yi1B - yiB) * invh - MiB * (HH / 3.0f) - Mi1B * (HH / 6.0f);
    const float cB = MiB * 0.5f;
    const float dB = (Mi1B - MiB) * inv6h;
    const float xlA = (float)idxA * HH;
    const float xlB = (float)idxB * HH;
    const float tb  = (float)((idxA + 1) * 819);   // first t belonging to span B

    // ---- curve + thread-local inclusive scan ----
    float loc[EPT];
    float running = 0.0f;
    #pragma unroll
    for (int k = 0; k < EPT; ++k) {
        float ft = (float)(t0 + k);
        bool inB = ft >= tb;
        float xl = inB ? xlB : xlA;
        float ca = inB ? aB : aA;
        float cb = inB ? bB : bA;
        float cc = inB ? cB : cA;
        float cd = inB ? dB : dA;
        float s  = ft - xl;
        running += fmaf(s, fmaf(s, fmaf(s, cd, cc), cb), ca);
        loc[k] = running;
    }

    // ---- wave scan (shfl) + cross-wave fixup (barrier 1) ----
    const int lane = tid & 63, wid = tid >> 6;
    float ws = running;
    #pragma unroll
    for (int d = 1; d < 64; d <<= 1) {
        float v = __shfl_up(ws, d, 64);
        if (lane >= d) ws += v;
    }
    if (lane == 63) sh_wsum[wid] = ws;
    __syncthreads();                            // B1
    float wo = 0.0f, total = 0.0f;
    #pragma unroll
    for (int w = 0; w < NWAVE; ++w) {
        float s = sh_wsum[w];
        total += s;
        if (w < wid) wo += s;
    }
    const float offs  = wo + (ws - running);    // exclusive prefix of this thread
    const float scale = 4095.0f / total;        // tt * (T-1) / tt_last

    float xpv[EPT + 1];
    #pragma unroll
    for (int k = 0; k < EPT; ++k)
        xpv[k] = (loc[k] + offs) * scale;
    sh_xx[tid] = xpv[0];
    __syncthreads();                            // B2: boundaries visible, bit-exact
    xpv[EPT]        = (tid < NTHR - 1) ? sh_xx[tid + 1] : 4095.0f;  // tid 511: unused
    const float fpb = (tid < NTHR - 1) ? sh_fx[tid + 1] : fpv[EPT - 1];

    // ---- direct forward scatter of final values ----
    // segment j owns q in [ceil(xp[j]), ceil(xp[j+1])-1]; boundaries shared
    // bit-exactly via sh_xx -> telescoping coverage, no gaps, avg 1 q/segment.
    #pragma unroll
    for (int k = 0; k < EPT; ++k) {
        const int seg = t0 + k;
        if (seg < TT - 1) {
            float xa = xpv[k], xb = xpv[k + 1];
            float fa = fpv[k];
            float fb = (k < EPT - 1) ? fpv[k + 1] : fpb;
            float d  = xb - xa;
            float slope = (d > 0.0f) ? (fb - fa) * __builtin_amdgcn_rcpf(d) : 0.0f;
            float a0 = fmaf(-xa, slope, fa);
            int qlo = (int)ceilf(xa);  if (qlo < 0) qlo = 0;
            int qhi = (int)ceilf(xb);  if (qhi > TT) qhi = TT;
            for (int q = qlo; q < qhi; ++q)
                sh_res[padi(q)] = fmaf((float)q, slope, a0);
        }
    }
    if (tid == 0) {                             // head: q < xp[0] -> fp[0]
        int q1 = (int)ceilf(xpv[0]);  if (q1 > TT) q1 = TT;
        for (int q = 0; q < q1; ++q) sh_res[padi(q)] = fpv[0];
    }
    if (tid == NTHR - 1) {                      // tail: q >= xp[4095] -> fp[4095]
        int q0 = (int)ceilf(xpv[EPT - 1]);  if (q0 < 0) q0 = 0;
        for (int q = q0; q < TT; ++q) sh_res[padi(q)] = fpv[EPT - 1];
    }
    __syncthreads();                            // B3: sh_res complete

    // ---- restage: coalesced nontemporal float4 stores ----
    // within a 32-float block, padded addresses stay contiguous, so
    // padi(base)+e is valid for e=0..3 when base%4==0
    #pragma unroll
    for (int kk = 0; kk < 2; ++kk) {
        int i4 = tid + NTHR * kk;
        int fb4 = 4 * i4;
        int p  = padi(fb4);
        f4 v;
        v.x = sh_res[p + 0];
        v.y = sh_res[p + 1];
        v.z = sh_res[p + 2];
        v.w = sh_res[p + 3];
        nt_store4(orow + fb4, v);
    }
}

extern "C" void kernel_launch(void* const* d_in, const int* in_sizes, int n_in,
                              void* d_out, int out_size, void* d_ws, size_t ws_size,
                              hipStream_t stream) {
    const float* x    = (const float*)d_in[0];   // (64,128,4096) fp32
    const float* yy   = (const float*)d_in[1];   // (64,6,128)    fp32
    const float* mask = (const float*)d_in[2];   // (64,1,1)      fp32
    float* out = (float*)d_out;                  // (64,128,4096) fp32
    timewarp_kernel<<<dim3(BB * CC), dim3(NTHR), 0, stream>>>(x, yy, mask, out);
}